// Round 5
// baseline (80.033 us; speedup 1.0000x reference)
//
#include <hip/hip_runtime.h>

// SpacialSeparation: sum over j>i of (||o_i - o_j||^2)^(1/4) * (labels differ ? -1 : 5)
// b = 8192, d = 64, fp32 in, fp32 scalar out.
//
// Round 4: augmented-Gram MFMA + fused deterministic reduction.
//   U_i = [-sqrt2*o_i, s_hi, s_lo, 1, 1, 0...]  (96 dims, bf16)
//   V_j = [ sqrt2*o_j, 1, 1, s_hi, s_lo, 0...]
//   => mfma dot(U_i, V_j) = s_i + s_j - 2<o_i,o_j> = d2 directly (K=96, 3 mfma/frag).
//   Block partials accumulate into one int64 (fixed-point 2^16) via device atomics
//   (order-invariant => deterministic); last block writes the float output.

typedef __bf16 bf16x8 __attribute__((ext_vector_type(8)));
typedef float  f32x4  __attribute__((ext_vector_type(4)));
typedef int    i32x4  __attribute__((ext_vector_type(4)));

#define BT   128
#define KAUG 96

__device__ __forceinline__ float qroot(float x) {          // x^(1/4)
    return __builtin_amdgcn_sqrtf(__builtin_amdgcn_sqrtf(x));
}
__device__ __forceinline__ unsigned short rne_bf16(float v) {
    const unsigned u = __builtin_bit_cast(unsigned, v);
    return (unsigned short)((u + 0x7fffu + ((u >> 16) & 1u)) >> 16);
}

// ---- prep: build augmented bf16 rows U, V; zero the atomic accumulators ----
__global__ __launch_bounds__(256)
void ss_prep(const float* __restrict__ O, unsigned short* __restrict__ U,
             unsigned short* __restrict__ V, unsigned long long* acc64,
             unsigned int* done) {
    const int row  = blockIdx.x * 4 + (threadIdx.x >> 6);
    const int lane = threadIdx.x & 63;
    const float v = O[(size_t)row * 64 + lane] * 1.4142135623730951f;
    const unsigned short w = rne_bf16(v);
    const float wf = __builtin_bit_cast(float, (unsigned)w << 16);
    float s = wf * wf * 0.5f;                      // sum -> ||o_bf||^2 (consistent)
    #pragma unroll
    for (int off = 32; off; off >>= 1) s += __shfl_xor(s, off);
    const unsigned short shi = rne_bf16(s);
    const float shif = __builtin_bit_cast(float, (unsigned)shi << 16);
    const unsigned short slo = rne_bf16(s - shif);

    unsigned short* urow = U + (size_t)row * KAUG;
    unsigned short* vrow = V + (size_t)row * KAUG;
    urow[lane] = (unsigned short)(w ^ 0x8000u);    // -w
    vrow[lane] = w;
    if (lane < 32) {
        const unsigned short one = 0x3F80;         // bf16(1.0)
        unsigned short tu = 0, tv = 0;
        if      (lane == 0) { tu = shi; tv = one; }
        else if (lane == 1) { tu = slo; tv = one; }
        else if (lane == 2) { tu = one; tv = shi; }
        else if (lane == 3) { tu = one; tv = slo; }
        urow[64 + lane] = tu;
        vrow[64 + lane] = tv;
    }
    if (blockIdx.x == 0 && threadIdx.x == 0) { *acc64 = 0ull; *done = 0u; }
}

// ---- main: fused Gram(d2) + epilogue + deterministic atomic reduction ----
__global__ __launch_bounds__(256, 4)
void ss_mfma(const unsigned short* __restrict__ U, const unsigned short* __restrict__ V,
             const int* __restrict__ L, unsigned long long* acc64, unsigned int* done,
             float* __restrict__ out, int nt, int ntri) {
    // decode linear block id -> upper-tri tile (ti, tj), ti <= tj
    const int t = blockIdx.x;
    const float fnt = (float)nt + 0.5f;
    int ti = (int)floorf(fnt - sqrtf(fnt * fnt - 2.0f * (float)t));
    if (ti < 0) ti = 0;
    if (ti > nt - 1) ti = nt - 1;
    while (ti > 0 && ti * nt - (ti * (ti - 1)) / 2 > t) --ti;
    while ((ti + 1) * nt - ((ti + 1) * ti) / 2 <= t) ++ti;
    const int tj = ti + (t - (ti * nt - (ti * (ti - 1)) / 2));

    const int tid  = threadIdx.x;
    const int wave = tid >> 6, lane = tid & 63;
    const int wr = wave >> 1, wc = wave & 1;
    const bool diag = (ti == tj);

    const int r0 = ti * BT + wr * 64;
    const int c0 = tj * BT + wc * 64;
    const int lrow = lane & 15;
    const int kq = lane >> 4;            // 0..3
    const int kb = kq * 8;               // k base within a K=32 chunk

    float accs = 0.0f;

    if (!(diag && (wc < wr))) {
        i32x4 li[4];                     // labels of this lane's C rows
        #pragma unroll
        for (int f = 0; f < 4; ++f)
            li[f] = *(const i32x4*)(L + r0 + f * 16 + (kq << 2));
        const bool masked = diag && (wr == wc);

        #pragma unroll
        for (int jh = 0; jh < 2; ++jh) {            // two 64x32 j-halves
            const int cj = c0 + jh * 32;

            bf16x8 bfr[2][3];
            #pragma unroll
            for (int g = 0; g < 2; ++g) {
                const unsigned short* pb = V + (size_t)(cj + g * 16 + lrow) * KAUG + kb;
                bfr[g][0] = *(const bf16x8*)pb;
                bfr[g][1] = *(const bf16x8*)(pb + 32);
                bfr[g][2] = *(const bf16x8*)(pb + 64);
            }

            f32x4 acc[4][2];
            #pragma unroll
            for (int i = 0; i < 4; ++i)
                #pragma unroll
                for (int g = 0; g < 2; ++g)
                    acc[i][g] = (f32x4){0.f, 0.f, 0.f, 0.f};

            #pragma unroll
            for (int i = 0; i < 4; ++i) {
                const unsigned short* pa = U + (size_t)(r0 + i * 16 + lrow) * KAUG + kb;
                const bf16x8 a0 = *(const bf16x8*)pa;
                const bf16x8 a1 = *(const bf16x8*)(pa + 32);
                const bf16x8 a2 = *(const bf16x8*)(pa + 64);
                #pragma unroll
                for (int g = 0; g < 2; ++g) {
                    acc[i][g] = __builtin_amdgcn_mfma_f32_16x16x32_bf16(a0, bfr[g][0], acc[i][g], 0, 0, 0);
                    acc[i][g] = __builtin_amdgcn_mfma_f32_16x16x32_bf16(a1, bfr[g][1], acc[i][g], 0, 0, 0);
                    acc[i][g] = __builtin_amdgcn_mfma_f32_16x16x32_bf16(a2, bfr[g][2], acc[i][g], 0, 0, 0);
                }
            }

            // ---- epilogue: acc IS d2 ----
            #pragma unroll
            for (int g = 0; g < 2; ++g) {
                const int j   = cj + g * 16 + lrow;
                const int ljv = L[j];
                if (masked) {
                    #pragma unroll
                    for (int fi = 0; fi < 4; ++fi) {
                        const int ib = r0 + fi * 16 + (kq << 2);
                        #pragma unroll
                        for (int r = 0; r < 4; ++r) {
                            const float d2   = fmaxf(acc[fi][g][r], 0.0f);
                            const float dist = qroot(d2);
                            const float fac  = (li[fi][r] != ljv) ? -1.0f : 5.0f;
                            accs += (j > ib + r) ? dist * fac : 0.0f;
                        }
                    }
                } else {
                    #pragma unroll
                    for (int fi = 0; fi < 4; ++fi) {
                        #pragma unroll
                        for (int r = 0; r < 4; ++r) {
                            const float d2   = fmaxf(acc[fi][g][r], 0.0f);
                            const float dist = qroot(d2);
                            const float fac  = (li[fi][r] != ljv) ? -1.0f : 5.0f;
                            accs = fmaf(dist, fac, accs);
                        }
                    }
                }
            }
        }
    }

    // ---- block reduction -> fixed-point atomic (order-invariant, deterministic) ----
    __shared__ float wsum[4];
    #pragma unroll
    for (int off = 32; off > 0; off >>= 1) accs += __shfl_down(accs, off);
    if (lane == 0) wsum[wave] = accs;
    __syncthreads();
    if (tid == 0) {
        const float bs = (wsum[0] + wsum[1]) + (wsum[2] + wsum[3]);
        const long long p = llrintf(bs * 65536.0f);
        atomicAdd(acc64, (unsigned long long)p);
        __threadfence();
        const unsigned prev = atomicAdd(done, 1u);
        if (prev == (unsigned)(ntri - 1)) {
            const unsigned long long tot = atomicAdd(acc64, 0ull);
            out[0] = (float)((double)(long long)tot / 65536.0);
        }
    }
}

extern "C" void kernel_launch(void* const* d_in, const int* in_sizes, int n_in,
                              void* d_out, int out_size, void* d_ws, size_t ws_size,
                              hipStream_t stream) {
    const float* O = (const float*)d_in[0];   // [b, 64] fp32
    const int*   L = (const int*)d_in[1];     // [b] int32
    float* out = (float*)d_out;               // scalar fp32

    const int b    = in_sizes[1];             // 8192
    const int nt   = b / BT;                  // 64
    const int ntri = nt * (nt + 1) / 2;       // 2080

    // workspace layout
    char* ws = (char*)d_ws;
    unsigned long long* acc64 = (unsigned long long*)ws;            // 8 B
    unsigned int*       done  = (unsigned int*)(ws + 8);            // 4 B
    unsigned short*     U     = (unsigned short*)(ws + 1024);       // b*96 bf16
    unsigned short*     V     = (unsigned short*)(ws + 1024 + (size_t)b * KAUG * 2);

    ss_prep<<<b / 4, 256, 0, stream>>>(O, U, V, acc64, done);
    ss_mfma<<<ntri, 256, 0, stream>>>(U, V, L, acc64, done, out, nt, ntri);
}

// Round 6
// 70.777 us; speedup vs baseline: 1.1308x; 1.1308x over previous
//
#include <hip/hip_runtime.h>

// SpacialSeparation: sum over j>i of (||o_i - o_j||^2)^(1/4) * (labels differ ? -1 : 5)
// b = 8192, d = 64, fp32 in, fp32 scalar out.
//
// Round 5: augmented-Gram MFMA with LDS-staged panels.
//   U_i = [-sqrt2*o_i, s_hi, s_lo, 1, 1, 0...]  (96 dims, bf16)
//   V_j = [ sqrt2*o_j, 1, 1, s_hi, s_lo, 0...]
//   => dot(U_i, V_j) = s_i + s_j - 2<o_i,o_j> = d2 directly (K=96, 3 mfma/frag).
//   Panels (128 rows x 96) reg-staged into LDS (stride 104 elems: 16B-aligned,
//   bank-uniform). Fragments ds_read from LDS -> remat is cheap, latency decoupled.
//   Deterministic fused reduction: fixed-point int64 atomics + done counter.

typedef __bf16 bf16x8 __attribute__((ext_vector_type(8)));
typedef float  f32x4  __attribute__((ext_vector_type(4)));
typedef int    i32x4  __attribute__((ext_vector_type(4)));

#define BT    128
#define KAUG  96
#define LSTR  104                 // LDS row stride in elements (208 B)
#define PANEL (128 * LSTR)        // elements per panel

__device__ __forceinline__ float qroot(float x) {          // x^(1/4)
    return __builtin_amdgcn_sqrtf(__builtin_amdgcn_sqrtf(x));
}
__device__ __forceinline__ unsigned short rne_bf16(float v) {
    const unsigned u = __builtin_bit_cast(unsigned, v);
    return (unsigned short)((u + 0x7fffu + ((u >> 16) & 1u)) >> 16);
}

// ---- prep: build augmented bf16 rows U, V; zero the atomic accumulators ----
__global__ __launch_bounds__(256)
void ss_prep(const float* __restrict__ O, unsigned short* __restrict__ U,
             unsigned short* __restrict__ V, unsigned long long* acc64,
             unsigned int* done) {
    const int row  = blockIdx.x * 4 + (threadIdx.x >> 6);
    const int lane = threadIdx.x & 63;
    const float v = O[(size_t)row * 64 + lane] * 1.4142135623730951f;
    const unsigned short w = rne_bf16(v);
    const float wf = __builtin_bit_cast(float, (unsigned)w << 16);
    float s = wf * wf * 0.5f;                      // -> ||o_bf||^2 (consistent)
    #pragma unroll
    for (int off = 32; off; off >>= 1) s += __shfl_xor(s, off);
    const unsigned short shi = rne_bf16(s);
    const float shif = __builtin_bit_cast(float, (unsigned)shi << 16);
    const unsigned short slo = rne_bf16(s - shif);

    unsigned short* urow = U + (size_t)row * KAUG;
    unsigned short* vrow = V + (size_t)row * KAUG;
    urow[lane] = (unsigned short)(w ^ 0x8000u);    // -w
    vrow[lane] = w;
    if (lane < 32) {
        const unsigned short one = 0x3F80;         // bf16(1.0)
        unsigned short tu = 0, tv = 0;
        if      (lane == 0) { tu = shi; tv = one; }
        else if (lane == 1) { tu = slo; tv = one; }
        else if (lane == 2) { tu = one; tv = shi; }
        else if (lane == 3) { tu = one; tv = slo; }
        urow[64 + lane] = tu;
        vrow[64 + lane] = tv;
    }
    if (blockIdx.x == 0 && threadIdx.x == 0) { *acc64 = 0ull; *done = 0u; }
}

// ---- main: LDS-staged Gram(d2) + epilogue + deterministic atomic reduction ----
__global__ __launch_bounds__(256, 3)
void ss_mfma(const unsigned short* __restrict__ U, const unsigned short* __restrict__ V,
             const int* __restrict__ L, unsigned long long* acc64, unsigned int* done,
             float* __restrict__ out, int nt, int ntri) {
    // decode linear block id -> upper-tri tile (ti, tj), ti <= tj
    const int t = blockIdx.x;
    const float fnt = (float)nt + 0.5f;
    int ti = (int)floorf(fnt - sqrtf(fnt * fnt - 2.0f * (float)t));
    if (ti < 0) ti = 0;
    if (ti > nt - 1) ti = nt - 1;
    while (ti > 0 && ti * nt - (ti * (ti - 1)) / 2 > t) --ti;
    while ((ti + 1) * nt - ((ti + 1) * ti) / 2 <= t) ++ti;
    const int tj = ti + (t - (ti * nt - (ti * (ti - 1)) / 2));

    const int tid  = threadIdx.x;
    const int wave = tid >> 6, lane = tid & 63;
    const int wr = wave >> 1, wc = wave & 1;
    const bool diag = (ti == tj);

    __shared__ unsigned short lds[2 * PANEL];      // 53,248 B
    __shared__ float wsum[4];

    // ---- stage both panels: 12 global b128 loads in flight, then 12 ds_writes ----
    {
        const unsigned short* srcU = U + (size_t)(ti * BT) * KAUG;  // contiguous panel
        const unsigned short* srcV = V + (size_t)(tj * BT) * KAUG;
        bf16x8 ru[6], rv[6];
        #pragma unroll
        for (int k = 0; k < 6; ++k) {
            const int id = k * 256 + tid;          // 16B-chunk id, 0..1535
            ru[k] = *(const bf16x8*)(srcU + id * 8);
            rv[k] = *(const bf16x8*)(srcV + id * 8);
        }
        #pragma unroll
        for (int k = 0; k < 6; ++k) {
            const int id  = k * 256 + tid;
            const int row = id / 12, col = id - row * 12;
            *(bf16x8*)(&lds[row * LSTR + col * 8])         = ru[k];
            *(bf16x8*)(&lds[PANEL + row * LSTR + col * 8]) = rv[k];
        }
    }
    __syncthreads();

    const int lrow = lane & 15;
    const int kq   = lane >> 4;          // 0..3
    const int r0   = ti * BT + wr * 64;  // global i-row base (labels)

    float accs = 0.0f;

    if (!(diag && (wc < wr))) {          // skip fully-lower subtile of diag blocks
        i32x4 li[4];
        #pragma unroll
        for (int f = 0; f < 4; ++f)
            li[f] = *(const i32x4*)(L + r0 + f * 16 + (kq << 2));
        const bool masked = diag && (wr == wc);

        // ---- A fragments from LDS, held across both j-halves ----
        bf16x8 afr[4][3];
        #pragma unroll
        for (int i = 0; i < 4; ++i) {
            const unsigned short* pa = &lds[(wr * 64 + i * 16 + lrow) * LSTR + kq * 8];
            afr[i][0] = *(const bf16x8*)pa;
            afr[i][1] = *(const bf16x8*)(pa + 32);
            afr[i][2] = *(const bf16x8*)(pa + 64);
        }

        #pragma unroll
        for (int jh = 0; jh < 2; ++jh) {            // two 64x32 j-halves
            bf16x8 bfr[2][3];
            #pragma unroll
            for (int g = 0; g < 2; ++g) {
                const unsigned short* pb =
                    &lds[PANEL + (wc * 64 + jh * 32 + g * 16 + lrow) * LSTR + kq * 8];
                bfr[g][0] = *(const bf16x8*)pb;
                bfr[g][1] = *(const bf16x8*)(pb + 32);
                bfr[g][2] = *(const bf16x8*)(pb + 64);
            }

            f32x4 acc[4][2];
            #pragma unroll
            for (int i = 0; i < 4; ++i)
                #pragma unroll
                for (int g = 0; g < 2; ++g)
                    acc[i][g] = (f32x4){0.f, 0.f, 0.f, 0.f};

            #pragma unroll
            for (int i = 0; i < 4; ++i)
                #pragma unroll
                for (int g = 0; g < 2; ++g) {
                    acc[i][g] = __builtin_amdgcn_mfma_f32_16x16x32_bf16(afr[i][0], bfr[g][0], acc[i][g], 0, 0, 0);
                    acc[i][g] = __builtin_amdgcn_mfma_f32_16x16x32_bf16(afr[i][1], bfr[g][1], acc[i][g], 0, 0, 0);
                    acc[i][g] = __builtin_amdgcn_mfma_f32_16x16x32_bf16(afr[i][2], bfr[g][2], acc[i][g], 0, 0, 0);
                }

            // ---- epilogue: acc IS d2 ----
            const int c0 = tj * BT + wc * 64 + jh * 32;
            #pragma unroll
            for (int g = 0; g < 2; ++g) {
                const int j   = c0 + g * 16 + lrow;
                const int ljv = L[j];
                if (masked) {
                    #pragma unroll
                    for (int fi = 0; fi < 4; ++fi) {
                        const int ib = r0 + fi * 16 + (kq << 2);
                        #pragma unroll
                        for (int r = 0; r < 4; ++r) {
                            const float d2   = fmaxf(acc[fi][g][r], 0.0f);
                            const float dist = qroot(d2);
                            const float fac  = (li[fi][r] != ljv) ? -1.0f : 5.0f;
                            accs += (j > ib + r) ? dist * fac : 0.0f;
                        }
                    }
                } else {
                    #pragma unroll
                    for (int fi = 0; fi < 4; ++fi) {
                        #pragma unroll
                        for (int r = 0; r < 4; ++r) {
                            const float d2   = fmaxf(acc[fi][g][r], 0.0f);
                            const float dist = qroot(d2);
                            const float fac  = (li[fi][r] != ljv) ? -1.0f : 5.0f;
                            accs = fmaf(dist, fac, accs);
                        }
                    }
                }
            }
        }
    }

    // ---- block reduction -> fixed-point atomic (order-invariant, deterministic) ----
    #pragma unroll
    for (int off = 32; off > 0; off >>= 1) accs += __shfl_down(accs, off);
    if (lane == 0) wsum[wave] = accs;
    __syncthreads();
    if (tid == 0) {
        const float bs = (wsum[0] + wsum[1]) + (wsum[2] + wsum[3]);
        const long long p = llrintf(bs * 65536.0f);
        atomicAdd(acc64, (unsigned long long)p);
        __threadfence();
        const unsigned prev = atomicAdd(done, 1u);
        if (prev == (unsigned)(ntri - 1)) {
            const unsigned long long tot = atomicAdd(acc64, 0ull);
            out[0] = (float)((double)(long long)tot / 65536.0);
        }
    }
}

extern "C" void kernel_launch(void* const* d_in, const int* in_sizes, int n_in,
                              void* d_out, int out_size, void* d_ws, size_t ws_size,
                              hipStream_t stream) {
    const float* O = (const float*)d_in[0];   // [b, 64] fp32
    const int*   L = (const int*)d_in[1];     // [b] int32
    float* out = (float*)d_out;               // scalar fp32

    const int b    = in_sizes[1];             // 8192
    const int nt   = b / BT;                  // 64
    const int ntri = nt * (nt + 1) / 2;       // 2080

    // workspace layout
    char* ws = (char*)d_ws;
    unsigned long long* acc64 = (unsigned long long*)ws;            // 8 B
    unsigned int*       done  = (unsigned int*)(ws + 8);            // 4 B
    unsigned short*     U     = (unsigned short*)(ws + 1024);       // b*96 bf16
    unsigned short*     V     = (unsigned short*)(ws + 1024 + (size_t)b * KAUG * 2);

    ss_prep<<<b / 4, 256, 0, stream>>>(O, U, V, acc64, done);
    ss_mfma<<<ntri, 256, 0, stream>>>(U, V, L, acc64, done, out, nt, ntri);
}

// Round 7
// 31.638 us; speedup vs baseline: 2.5297x; 2.2371x over previous
//
#include <hip/hip_runtime.h>

// SpacialSeparation: sum over j>i of (||o_i - o_j||^2)^(1/4) * (labels differ ? -1 : 5)
// b = 8192, d = 64, fp32 in, fp32 scalar out.
//
// Round 6: round-5 LDS-staged augmented-Gram core, but reduction reverted to the
// contention-free r3 structure (per-block partials store + tiny reduce kernel).
// r4/r5's single-cacheline device atomics serialized ~2x2080 RMWs across 8
// non-coherent XCDs -> ~66 us floor with all pipes idle.

typedef __bf16 bf16x8 __attribute__((ext_vector_type(8)));
typedef float  f32x4  __attribute__((ext_vector_type(4)));
typedef int    i32x4  __attribute__((ext_vector_type(4)));

#define BT    128
#define KAUG  96
#define LSTR  104                 // LDS row stride in elements (208 B)
#define PANEL (128 * LSTR)        // elements per panel

__device__ __forceinline__ float qroot(float x) {          // x^(1/4)
    return __builtin_amdgcn_sqrtf(__builtin_amdgcn_sqrtf(x));
}
__device__ __forceinline__ unsigned short rne_bf16(float v) {
    const unsigned u = __builtin_bit_cast(unsigned, v);
    return (unsigned short)((u + 0x7fffu + ((u >> 16) & 1u)) >> 16);
}

// ---- prep: build augmented bf16 rows U, V ----
__global__ __launch_bounds__(256)
void ss_prep(const float* __restrict__ O, unsigned short* __restrict__ U,
             unsigned short* __restrict__ V) {
    const int row  = blockIdx.x * 4 + (threadIdx.x >> 6);
    const int lane = threadIdx.x & 63;
    const float v = O[(size_t)row * 64 + lane] * 1.4142135623730951f;
    const unsigned short w = rne_bf16(v);
    const float wf = __builtin_bit_cast(float, (unsigned)w << 16);
    float s = wf * wf * 0.5f;                      // -> ||o_bf||^2 (consistent)
    #pragma unroll
    for (int off = 32; off; off >>= 1) s += __shfl_xor(s, off);
    const unsigned short shi = rne_bf16(s);
    const float shif = __builtin_bit_cast(float, (unsigned)shi << 16);
    const unsigned short slo = rne_bf16(s - shif);

    unsigned short* urow = U + (size_t)row * KAUG;
    unsigned short* vrow = V + (size_t)row * KAUG;
    urow[lane] = (unsigned short)(w ^ 0x8000u);    // -w
    vrow[lane] = w;
    if (lane < 32) {
        const unsigned short one = 0x3F80;         // bf16(1.0)
        unsigned short tu = 0, tv = 0;
        if      (lane == 0) { tu = shi; tv = one; }
        else if (lane == 1) { tu = slo; tv = one; }
        else if (lane == 2) { tu = one; tv = shi; }
        else if (lane == 3) { tu = one; tv = slo; }
        urow[64 + lane] = tu;
        vrow[64 + lane] = tv;
    }
}

// ---- main: LDS-staged Gram(d2) + epilogue; per-block partial store ----
__global__ __launch_bounds__(256, 3)
void ss_mfma(const unsigned short* __restrict__ U, const unsigned short* __restrict__ V,
             const int* __restrict__ L, float* __restrict__ partials, int nt) {
    // decode linear block id -> upper-tri tile (ti, tj), ti <= tj
    const int t = blockIdx.x;
    const float fnt = (float)nt + 0.5f;
    int ti = (int)floorf(fnt - sqrtf(fnt * fnt - 2.0f * (float)t));
    if (ti < 0) ti = 0;
    if (ti > nt - 1) ti = nt - 1;
    while (ti > 0 && ti * nt - (ti * (ti - 1)) / 2 > t) --ti;
    while ((ti + 1) * nt - ((ti + 1) * ti) / 2 <= t) ++ti;
    const int tj = ti + (t - (ti * nt - (ti * (ti - 1)) / 2));

    const int tid  = threadIdx.x;
    const int wave = tid >> 6, lane = tid & 63;
    const int wr = wave >> 1, wc = wave & 1;
    const bool diag = (ti == tj);

    __shared__ unsigned short lds[2 * PANEL];      // 53,248 B
    __shared__ float wsum[4];

    // ---- stage both panels: 12 global b128 loads in flight, then 12 ds_writes ----
    {
        const unsigned short* srcU = U + (size_t)(ti * BT) * KAUG;  // contiguous panel
        const unsigned short* srcV = V + (size_t)(tj * BT) * KAUG;
        bf16x8 ru[6], rv[6];
        #pragma unroll
        for (int k = 0; k < 6; ++k) {
            const int id = k * 256 + tid;          // 16B-chunk id, 0..1535
            ru[k] = *(const bf16x8*)(srcU + id * 8);
            rv[k] = *(const bf16x8*)(srcV + id * 8);
        }
        #pragma unroll
        for (int k = 0; k < 6; ++k) {
            const int id  = k * 256 + tid;
            const int row = id / 12, col = id - row * 12;
            *(bf16x8*)(&lds[row * LSTR + col * 8])         = ru[k];
            *(bf16x8*)(&lds[PANEL + row * LSTR + col * 8]) = rv[k];
        }
    }
    __syncthreads();

    const int lrow = lane & 15;
    const int kq   = lane >> 4;          // 0..3
    const int r0   = ti * BT + wr * 64;  // global i-row base (labels)

    float accs = 0.0f;

    if (!(diag && (wc < wr))) {          // skip fully-lower subtile of diag blocks
        i32x4 li[4];
        #pragma unroll
        for (int f = 0; f < 4; ++f)
            li[f] = *(const i32x4*)(L + r0 + f * 16 + (kq << 2));
        const bool masked = diag && (wr == wc);

        // ---- A fragments from LDS, held across both j-halves ----
        bf16x8 afr[4][3];
        #pragma unroll
        for (int i = 0; i < 4; ++i) {
            const unsigned short* pa = &lds[(wr * 64 + i * 16 + lrow) * LSTR + kq * 8];
            afr[i][0] = *(const bf16x8*)pa;
            afr[i][1] = *(const bf16x8*)(pa + 32);
            afr[i][2] = *(const bf16x8*)(pa + 64);
        }

        #pragma unroll
        for (int jh = 0; jh < 2; ++jh) {            // two 64x32 j-halves
            bf16x8 bfr[2][3];
            #pragma unroll
            for (int g = 0; g < 2; ++g) {
                const unsigned short* pb =
                    &lds[PANEL + (wc * 64 + jh * 32 + g * 16 + lrow) * LSTR + kq * 8];
                bfr[g][0] = *(const bf16x8*)pb;
                bfr[g][1] = *(const bf16x8*)(pb + 32);
                bfr[g][2] = *(const bf16x8*)(pb + 64);
            }

            f32x4 acc[4][2];
            #pragma unroll
            for (int i = 0; i < 4; ++i)
                #pragma unroll
                for (int g = 0; g < 2; ++g)
                    acc[i][g] = (f32x4){0.f, 0.f, 0.f, 0.f};

            #pragma unroll
            for (int i = 0; i < 4; ++i)
                #pragma unroll
                for (int g = 0; g < 2; ++g) {
                    acc[i][g] = __builtin_amdgcn_mfma_f32_16x16x32_bf16(afr[i][0], bfr[g][0], acc[i][g], 0, 0, 0);
                    acc[i][g] = __builtin_amdgcn_mfma_f32_16x16x32_bf16(afr[i][1], bfr[g][1], acc[i][g], 0, 0, 0);
                    acc[i][g] = __builtin_amdgcn_mfma_f32_16x16x32_bf16(afr[i][2], bfr[g][2], acc[i][g], 0, 0, 0);
                }

            // ---- epilogue: acc IS d2 ----
            const int c0 = tj * BT + wc * 64 + jh * 32;
            #pragma unroll
            for (int g = 0; g < 2; ++g) {
                const int j   = c0 + g * 16 + lrow;
                const int ljv = L[j];
                if (masked) {
                    #pragma unroll
                    for (int fi = 0; fi < 4; ++fi) {
                        const int ib = r0 + fi * 16 + (kq << 2);
                        #pragma unroll
                        for (int r = 0; r < 4; ++r) {
                            const float d2   = fmaxf(acc[fi][g][r], 0.0f);
                            const float dist = qroot(d2);
                            const float fac  = (li[fi][r] != ljv) ? -1.0f : 5.0f;
                            accs += (j > ib + r) ? dist * fac : 0.0f;
                        }
                    }
                } else {
                    #pragma unroll
                    for (int fi = 0; fi < 4; ++fi) {
                        #pragma unroll
                        for (int r = 0; r < 4; ++r) {
                            const float d2   = fmaxf(acc[fi][g][r], 0.0f);
                            const float dist = qroot(d2);
                            const float fac  = (li[fi][r] != ljv) ? -1.0f : 5.0f;
                            accs = fmaf(dist, fac, accs);
                        }
                    }
                }
            }
        }
    }

    // ---- block reduction -> plain partials store (contention-free) ----
    #pragma unroll
    for (int off = 32; off > 0; off >>= 1) accs += __shfl_down(accs, off);
    if (lane == 0) wsum[wave] = accs;
    __syncthreads();
    if (tid == 0) partials[t] = (wsum[0] + wsum[1]) + (wsum[2] + wsum[3]);
}

__global__ void ss_reduce_kernel(const float* __restrict__ partials, int n,
                                 float* __restrict__ out) {
    __shared__ float s[4];
    const int tid = threadIdx.x;
    float acc = 0.0f;
    for (int idx = tid; idx < n; idx += 256) acc += partials[idx];
    #pragma unroll
    for (int off = 32; off > 0; off >>= 1) acc += __shfl_down(acc, off);
    if ((tid & 63) == 0) s[tid >> 6] = acc;
    __syncthreads();
    if (tid == 0) out[0] = (s[0] + s[1]) + (s[2] + s[3]);
}

extern "C" void kernel_launch(void* const* d_in, const int* in_sizes, int n_in,
                              void* d_out, int out_size, void* d_ws, size_t ws_size,
                              hipStream_t stream) {
    const float* O = (const float*)d_in[0];   // [b, 64] fp32
    const int*   L = (const int*)d_in[1];     // [b] int32
    float* out = (float*)d_out;               // scalar fp32

    const int b    = in_sizes[1];             // 8192
    const int nt   = b / BT;                  // 64
    const int ntri = nt * (nt + 1) / 2;       // 2080

    // workspace layout
    char* ws = (char*)d_ws;
    float*          partials = (float*)ws;                          // ntri floats
    unsigned short* U        = (unsigned short*)(ws + (64 << 10));  // b*96 bf16
    unsigned short* V        = (unsigned short*)(ws + (64 << 10) + (size_t)b * KAUG * 2);

    ss_prep<<<b / 4, 256, 0, stream>>>(O, U, V);
    ss_mfma<<<ntri, 256, 0, stream>>>(U, V, L, partials, nt);
    ss_reduce_kernel<<<1, 256, 0, stream>>>(partials, ntri, out);
}

// Round 8
// 28.790 us; speedup vs baseline: 2.7799x; 1.0989x over previous
//
#include <hip/hip_runtime.h>

// SpacialSeparation: sum over j>i of (||o_i - o_j||^2)^(1/4) * (labels differ ? -1 : 5)
// b = 8192, d = 64, fp32 in, fp32 scalar out.
//
// Round 7: plain K=64 Gram (d2 = si + sj - 2<oi,oj>), LDS-staged, 4 blocks/CU.
//   r6's K=96 augmentation cost 50% more MFMA/staging and bound occupancy at
//   3 blocks/CU via 53KB LDS; epilogue saving was ~1.5 VALU/pair. Reverting K=64
//   shrinks LDS to 36,864B -> 4 blocks/CU (16 waves/CU) and halves stage traffic.
//   Reduction stays contention-free (per-block partials + tiny reduce kernel).

typedef __bf16 bf16x8 __attribute__((ext_vector_type(8)));
typedef float  f32x4  __attribute__((ext_vector_type(4)));
typedef int    i32x4  __attribute__((ext_vector_type(4)));

#define BT    128
#define DK    64
#define LSTR  72                  // LDS row stride in elements (144 B)
#define PANEL (128 * LSTR)        // 9216 elements = 18,432 B per panel

__device__ __forceinline__ float qroot(float x) {          // x^(1/4)
    return __builtin_amdgcn_sqrtf(__builtin_amdgcn_sqrtf(x));
}
__device__ __forceinline__ unsigned short rne_bf16(float v) {
    const unsigned u = __builtin_bit_cast(unsigned, v);
    return (unsigned short)((u + 0x7fffu + ((u >> 16) & 1u)) >> 16);
}

// ---- prep: fp32 -> bf16 (RNE) + row squared norms of the rounded values ----
__global__ __launch_bounds__(256)
void ss_prep(const float* __restrict__ O, unsigned short* __restrict__ Obf,
             float* __restrict__ sqb) {
    const int row  = blockIdx.x * 4 + (threadIdx.x >> 6);
    const int lane = threadIdx.x & 63;
    const float v = O[(size_t)row * 64 + lane];
    const unsigned short w = rne_bf16(v);
    Obf[(size_t)row * 64 + lane] = w;
    const float wf = __builtin_bit_cast(float, (unsigned)w << 16);
    float s = wf * wf;
    #pragma unroll
    for (int off = 32; off; off >>= 1) s += __shfl_xor(s, off);
    if (lane == 0) sqb[row] = s;
}

// ---- main: LDS-staged Gram + epilogue; per-block partial store ----
__global__ __launch_bounds__(256, 4)
void ss_mfma(const unsigned short* __restrict__ Obf, const float* __restrict__ sqb,
             const int* __restrict__ L, float* __restrict__ partials, int nt) {
    // decode linear block id -> upper-tri tile (ti, tj), ti <= tj
    const int t = blockIdx.x;
    const float fnt = (float)nt + 0.5f;
    int ti = (int)floorf(fnt - sqrtf(fnt * fnt - 2.0f * (float)t));
    if (ti < 0) ti = 0;
    if (ti > nt - 1) ti = nt - 1;
    while (ti > 0 && ti * nt - (ti * (ti - 1)) / 2 > t) --ti;
    while ((ti + 1) * nt - ((ti + 1) * ti) / 2 <= t) ++ti;
    const int tj = ti + (t - (ti * nt - (ti * (ti - 1)) / 2));

    const int tid  = threadIdx.x;
    const int wave = tid >> 6, lane = tid & 63;
    const int wr = wave >> 1, wc = wave & 1;
    const bool diag = (ti == tj);

    __shared__ unsigned short lds[2 * PANEL];      // 36,864 B
    __shared__ float wsum[4];

    // ---- stage both panels: 8 global b128 loads in flight, then 8 ds_writes ----
    {
        const unsigned short* srcA = Obf + (size_t)(ti * BT) * DK;  // contiguous panels
        const unsigned short* srcB = Obf + (size_t)(tj * BT) * DK;
        bf16x8 ra[4], rb[4];
        #pragma unroll
        for (int k = 0; k < 4; ++k) {
            const int id = k * 256 + tid;          // 16B-chunk id, 0..1023
            ra[k] = *(const bf16x8*)(srcA + id * 8);
            rb[k] = *(const bf16x8*)(srcB + id * 8);
        }
        #pragma unroll
        for (int k = 0; k < 4; ++k) {
            const int id  = k * 256 + tid;
            const int row = id >> 3, col = id & 7;
            *(bf16x8*)(&lds[row * LSTR + col * 8])         = ra[k];
            *(bf16x8*)(&lds[PANEL + row * LSTR + col * 8]) = rb[k];
        }
    }
    __syncthreads();

    const int lrow = lane & 15;
    const int kq   = lane >> 4;          // 0..3
    const int r0   = ti * BT + wr * 64;  // global i-row base

    float accs = 0.0f;

    if (!(diag && (wc < wr))) {          // skip fully-lower subtile of diag blocks
        // i-side metadata (C/D rows: kq*4 + r  [m89])
        f32x4 sqi[4]; i32x4 li[4];
        #pragma unroll
        for (int f = 0; f < 4; ++f) {
            const int ib = r0 + f * 16 + (kq << 2);
            sqi[f] = *(const f32x4*)(sqb + ib);
            li[f]  = *(const i32x4*)(L + ib);
        }
        const bool masked = diag && (wr == wc);

        // ---- A fragments from LDS (held or remat'd from LDS -- both cheap) ----
        bf16x8 afr[4][2];
        #pragma unroll
        for (int i = 0; i < 4; ++i) {
            const unsigned short* pa = &lds[(wr * 64 + i * 16 + lrow) * LSTR + kq * 8];
            afr[i][0] = *(const bf16x8*)pa;
            afr[i][1] = *(const bf16x8*)(pa + 32);
        }

        #pragma unroll
        for (int jh = 0; jh < 2; ++jh) {            // two 64x32 j-halves
            bf16x8 bfr[2][2];
            #pragma unroll
            for (int g = 0; g < 2; ++g) {
                const unsigned short* pb =
                    &lds[PANEL + (wc * 64 + jh * 32 + g * 16 + lrow) * LSTR + kq * 8];
                bfr[g][0] = *(const bf16x8*)pb;
                bfr[g][1] = *(const bf16x8*)(pb + 32);
            }

            f32x4 acc[4][2];
            #pragma unroll
            for (int i = 0; i < 4; ++i)
                #pragma unroll
                for (int g = 0; g < 2; ++g)
                    acc[i][g] = (f32x4){0.f, 0.f, 0.f, 0.f};

            #pragma unroll
            for (int i = 0; i < 4; ++i)
                #pragma unroll
                for (int g = 0; g < 2; ++g) {
                    acc[i][g] = __builtin_amdgcn_mfma_f32_16x16x32_bf16(afr[i][0], bfr[g][0], acc[i][g], 0, 0, 0);
                    acc[i][g] = __builtin_amdgcn_mfma_f32_16x16x32_bf16(afr[i][1], bfr[g][1], acc[i][g], 0, 0, 0);
                }

            // ---- epilogue: d2 = si + sj - 2*gram ----
            const int c0 = tj * BT + wc * 64 + jh * 32;
            #pragma unroll
            for (int g = 0; g < 2; ++g) {
                const int j    = c0 + g * 16 + lrow;
                const float sj = sqb[j];
                const int  ljv = L[j];
                if (masked) {
                    #pragma unroll
                    for (int fi = 0; fi < 4; ++fi) {
                        const int ib = r0 + fi * 16 + (kq << 2);
                        #pragma unroll
                        for (int r = 0; r < 4; ++r) {
                            float d2 = fmaf(-2.0f, acc[fi][g][r], sqi[fi][r] + sj);
                            d2 = fmaxf(d2, 0.0f);
                            const float dist = qroot(d2);
                            const float fac  = (li[fi][r] != ljv) ? -1.0f : 5.0f;
                            accs += (j > ib + r) ? dist * fac : 0.0f;
                        }
                    }
                } else {
                    #pragma unroll
                    for (int fi = 0; fi < 4; ++fi) {
                        #pragma unroll
                        for (int r = 0; r < 4; ++r) {
                            float d2 = fmaf(-2.0f, acc[fi][g][r], sqi[fi][r] + sj);
                            d2 = fmaxf(d2, 0.0f);
                            const float dist = qroot(d2);
                            const float fac  = (li[fi][r] != ljv) ? -1.0f : 5.0f;
                            accs = fmaf(dist, fac, accs);
                        }
                    }
                }
            }
        }
    }

    // ---- block reduction -> plain partials store (contention-free) ----
    #pragma unroll
    for (int off = 32; off > 0; off >>= 1) accs += __shfl_down(accs, off);
    if (lane == 0) wsum[wave] = accs;
    __syncthreads();
    if (tid == 0) partials[t] = (wsum[0] + wsum[1]) + (wsum[2] + wsum[3]);
}

__global__ void ss_reduce_kernel(const float* __restrict__ partials, int n,
                                 float* __restrict__ out) {
    __shared__ float s[4];
    const int tid = threadIdx.x;
    float acc = 0.0f;
    for (int idx = tid; idx < n; idx += 256) acc += partials[idx];
    #pragma unroll
    for (int off = 32; off > 0; off >>= 1) acc += __shfl_down(acc, off);
    if ((tid & 63) == 0) s[tid >> 6] = acc;
    __syncthreads();
    if (tid == 0) out[0] = (s[0] + s[1]) + (s[2] + s[3]);
}

extern "C" void kernel_launch(void* const* d_in, const int* in_sizes, int n_in,
                              void* d_out, int out_size, void* d_ws, size_t ws_size,
                              hipStream_t stream) {
    const float* O = (const float*)d_in[0];   // [b, 64] fp32
    const int*   L = (const int*)d_in[1];     // [b] int32
    float* out = (float*)d_out;               // scalar fp32

    const int b    = in_sizes[1];             // 8192
    const int nt   = b / BT;                  // 64
    const int ntri = nt * (nt + 1) / 2;       // 2080

    // workspace layout
    char* ws = (char*)d_ws;
    float*          partials = (float*)ws;                          // ntri floats
    float*          sqb      = (float*)(ws + (64 << 10));           // b floats
    unsigned short* Obf      = (unsigned short*)(ws + (128 << 10)); // b*64 bf16

    ss_prep<<<b / 4, 256, 0, stream>>>(O, Obf, sqb);
    ss_mfma<<<ntri, 256, 0, stream>>>(Obf, sqb, L, partials, nt);
    ss_reduce_kernel<<<1, 256, 0, stream>>>(partials, ntri, out);
}